// Round 8
// baseline (210.561 us; speedup 1.0000x reference)
//
#include <hip/hip_runtime.h>
#include <stdint.h>

#define BATCH 8
#define CIN   64
#define DH    32
#define NTOK  4096
#define LOG2E 1.4426950408889634f

typedef float    f4   __attribute__((ext_vector_type(4)));
typedef short    s8v  __attribute__((ext_vector_type(8)));
typedef uint32_t u32;
typedef uint32_t u32x2 __attribute__((ext_vector_type(2)));
typedef uint32_t u32x4 __attribute__((ext_vector_type(4)));

static __device__ __forceinline__ short f2bf(float f) {       // RNE
    union { float f; u32 u; } c; c.f = f;
    u32 u = c.u;
    u32 r = (u + 0x7fffu + ((u >> 16) & 1u)) >> 16;
    return (short)(r & 0xffffu);
}
static __device__ __forceinline__ u32 pk2(float a, float b) { // RNE pack
    return (u32)(uint16_t)f2bf(a) | ((u32)(uint16_t)f2bf(b) << 16);
}
static __device__ __forceinline__ u32 pktr(float a, float b) { // truncate pack (fast)
    union { float f; u32 u; } ca, cb; ca.f = a; cb.f = b;
#if __has_builtin(__builtin_amdgcn_perm)
    return __builtin_amdgcn_perm(cb.u, ca.u, 0x07060302u);
#else
    return (cb.u & 0xffff0000u) | (ca.u >> 16);
#endif
}
static __device__ __forceinline__ float bfhi(u32 u) {
    union { u32 u; float f; } c; c.u = u & 0xffff0000u; return c.f;
}
static __device__ __forceinline__ float bflo(u32 u) {
    union { u32 u; float f; } c; c.u = u << 16; return c.f;
}

// ---------------------------------------------------------------------------
// Kernel 1: MFMA QKV projection (unchanged since round 4 — passed, ~4 us).
// ---------------------------------------------------------------------------
__global__ __launch_bounds__(256) void proj_kernel(
    const float* __restrict__ h,
    const float* __restrict__ wq, const float* __restrict__ bq,
    const float* __restrict__ wk, const float* __restrict__ bk,
    const float* __restrict__ wv, const float* __restrict__ bv,
    short* __restrict__ qbf, short* __restrict__ kbf, short* __restrict__ vp)
{
    __shared__ short xT [64 * 72];   // [n_local][c] bf16
    __shared__ short wqs[32 * 72];   // [o][c] bf16 (pre-scaled by log2e)
    __shared__ short wks[32 * 72];
    __shared__ short wvs[64 * 72];
    __shared__ short vls2[64 * 68];  // [row=cid2*32+qq*8+j][ch], pad 68
    __shared__ float bqs[32], bks[32], bvs[64];

    const int t   = threadIdx.x;
    const int b   = blockIdx.x;
    const int nt0 = blockIdx.y * 64;

    { // stage x tile: coalesced global reads, bf16 transpose into LDS
        const int c  = t >> 2;
        const int ng = (t & 3) * 16;
        const float* src = h + ((size_t)(b * CIN + c)) * NTOK + nt0 + ng;
        f4 x0 = *(const f4*)(src + 0);
        f4 x1 = *(const f4*)(src + 4);
        f4 x2 = *(const f4*)(src + 8);
        f4 x3 = *(const f4*)(src + 12);
        #pragma unroll
        for (int i = 0; i < 4; ++i) {
            xT[(ng + 0  + i) * 72 + c] = f2bf(x0[i]);
            xT[(ng + 4  + i) * 72 + c] = f2bf(x1[i]);
            xT[(ng + 8  + i) * 72 + c] = f2bf(x2[i]);
            xT[(ng + 12 + i) * 72 + c] = f2bf(x3[i]);
        }
    }
    for (int idx = t; idx < 2048; idx += 256) {
        int o = idx >> 6, c = idx & 63;
        wqs[o * 72 + c] = f2bf(wq[idx] * LOG2E);
        wks[o * 72 + c] = f2bf(wk[idx]);
    }
    for (int idx = t; idx < 4096; idx += 256)
        wvs[(idx >> 6) * 72 + (idx & 63)] = f2bf(wv[idx]);
    if (t < 32) { bqs[t] = bq[t] * LOG2E; bks[t] = bk[t]; }
    if (t < 64) bvs[t] = bv[t];
    __syncthreads();

    const int w    = t >> 6;
    const int ln   = t & 15;
    const int quad = (t >> 4) & 3;
    const int nl   = w * 16 + ln;
    const int n    = nt0 + nl;
    const f4 zf4 = {0.f, 0.f, 0.f, 0.f};

    const s8v xb0 = *(const s8v*)&xT[nl * 72 + quad * 8];
    const s8v xb1 = *(const s8v*)&xT[nl * 72 + 32 + quad * 8];

    #pragma unroll
    for (int ot = 0; ot < 2; ++ot) {
        s8v a0 = *(const s8v*)&wqs[(ot * 16 + ln) * 72 + quad * 8];
        s8v a1 = *(const s8v*)&wqs[(ot * 16 + ln) * 72 + 32 + quad * 8];
        f4 d = __builtin_amdgcn_mfma_f32_16x16x32_bf16(a0, xb0, zf4, 0, 0, 0);
        d     = __builtin_amdgcn_mfma_f32_16x16x32_bf16(a1, xb1, d,  0, 0, 0);
        f4 bb = *(const f4*)&bqs[ot * 16 + quad * 4];
        u32x2 pw; pw[0] = pk2(d[0] + bb[0], d[1] + bb[1]);
                  pw[1] = pk2(d[2] + bb[2], d[3] + bb[3]);
        *(u32x2*)(qbf + ((size_t)(b * NTOK + n)) * DH + ot * 16 + quad * 4) = pw;

        s8v c0 = *(const s8v*)&wks[(ot * 16 + ln) * 72 + quad * 8];
        s8v c1 = *(const s8v*)&wks[(ot * 16 + ln) * 72 + 32 + quad * 8];
        f4 e = __builtin_amdgcn_mfma_f32_16x16x32_bf16(c0, xb0, zf4, 0, 0, 0);
        e     = __builtin_amdgcn_mfma_f32_16x16x32_bf16(c1, xb1, e,  0, 0, 0);
        f4 kb = *(const f4*)&bks[ot * 16 + quad * 4];
        u32x2 kw; kw[0] = pk2(e[0] + kb[0], e[1] + kb[1]);
                  kw[1] = pk2(e[2] + kb[2], e[3] + kb[3]);
        *(u32x2*)(kbf + ((size_t)(b * NTOK + n)) * DH + ot * 16 + quad * 4) = kw;
    }

    {
        const int p    = nl & 31;
        const int row  = (nl >> 5) * 32 + ((p >> 2) & 3) * 8
                       + (p >> 4) * 4 + (p & 3);
        short* vrow = &vls2[row * 68];
        #pragma unroll
        for (int ot = 0; ot < 4; ++ot) {
            s8v a0 = *(const s8v*)&wvs[(ot * 16 + ln) * 72 + quad * 8];
            s8v a1 = *(const s8v*)&wvs[(ot * 16 + ln) * 72 + 32 + quad * 8];
            f4 d = __builtin_amdgcn_mfma_f32_16x16x32_bf16(a0, xb0, zf4, 0, 0, 0);
            d     = __builtin_amdgcn_mfma_f32_16x16x32_bf16(a1, xb1, d,  0, 0, 0);
            const int ch = ot * 16 + quad * 4;
            u32x2 pw;
            pw[0] = pk2(d[0] + bvs[ch],     d[1] + bvs[ch + 1]);
            pw[1] = pk2(d[2] + bvs[ch + 2], d[3] + bvs[ch + 3]);
            *(u32x2*)&vrow[ch] = pw;
        }
    }
    __syncthreads();

    {
        const int g = t >> 5;
        const int r = t & 31;
        short tmp[16];
        #pragma unroll
        for (int j = 0; j < 8; ++j)
            #pragma unroll
            for (int cc = 0; cc < 2; ++cc)
                tmp[cc * 8 + j] = vls2[(g * 8 + j) * 68 + r * 2 + cc];
        u32x4* dst = (u32x4*)(vp + ((size_t)(b * 128 + blockIdx.y * 2) * 4) * 64 * 8);
        #pragma unroll
        for (int i = 0; i < 2; ++i)
            dst[t * 2 + i] = ((const u32x4*)tmp)[i];
    }
}

// ---------------------------------------------------------------------------
// Kernel 2: max-free flash attention + Wz projection + residual.
// TLP instead of ILP (R6/R7's source pipelining was vetoed by the compiler:
// VGPR stayed 80, time stayed 45us): 512-thr / 8-wave blocks, wave = one
// key-EIGHTH (512 keys) x 64 queries, grid (8,64) -> 2 blocks/CU =
// 16 waves/CU = 4 waves/SIMD (2x R4-R7) to cover the per-iter L2 latency.
// L2 traffic unchanged (waves partition keys within a block). K-loop is the
// proven R4 plain compiler-scheduled form. Combine: single-phase 8-slot
// elementwise sum by all 512 threads; zbuf aliases slots after a barrier.
// ---------------------------------------------------------------------------
__global__ __launch_bounds__(512, 4) void attn_kernel(
    const float* __restrict__ h,  const float* __restrict__ wz,
    const float* __restrict__ bz,
    const short* __restrict__ qbf, const short* __restrict__ kbf,
    const short* __restrict__ vp,  float* __restrict__ out)
{
    __shared__ short slots[8][64 * 68];   // 8 partial slots, 69.6 KB, pad 68
    __shared__ float lbuf[8][64];         // per-wave partial l
    short* zbuf = (short*)slots;          // reused after combine, stride 72

    const int b    = blockIdx.x;          // XCD-affine: linear%8 == b
    const int qb0  = blockIdx.y * 64;
    const int tid  = threadIdx.x;
    const int w    = tid >> 6;            // wave = key eighth
    const int lane = tid & 63;
    const int ln   = lane & 15;
    const int quad = lane >> 4;
    const f4 zf4 = {0.f, 0.f, 0.f, 0.f};

    // Q fragments (B-operand): B[d=quad*8+j][n=ln]
    s8v qf[4];
    #pragma unroll
    for (int f = 0; f < 4; ++f)
        qf[f] = *(const s8v*)(qbf + ((size_t)(b * NTOK + qb0 + f * 16 + ln)) * DH + quad * 8);

    f4 acc[4][4];
    f4 accl[4];
    #pragma unroll
    for (int f = 0; f < 4; ++f) {
        accl[f] = zf4;
        #pragma unroll
        for (int ct = 0; ct < 4; ++ct) acc[f][ct] = zf4;
    }
    s8v ones;
    #pragma unroll
    for (int j = 0; j < 8; ++j) ones[j] = (short)0x3F80;   // bf16 1.0

    const short* kb2 = kbf + ((size_t)b * NTOK + w * 512) * DH;
    const s8v*   vb2 = (const s8v*)(vp + (size_t)b * NTOK * CIN)
                     + (size_t)(w * 16) * 4 * 64;

    for (int kt = 0; kt < 512; kt += 32) {
        const short* kp = kb2 + kt * DH;
        s8v kk0 = *(const s8v*)(kp + ln * DH + quad * 8);
        s8v kk1 = *(const s8v*)(kp + (16 + ln) * DH + quad * 8);
        const s8v* vg = vb2 + (size_t)((kt >> 5) * 4 + quad) * 64 + ln;
        s8v v0 = vg[0], v1 = vg[16], v2 = vg[32], v3 = vg[48];

        #pragma unroll
        for (int f = 0; f < 4; ++f) {
            f4 sa = __builtin_amdgcn_mfma_f32_16x16x32_bf16(kk0, qf[f], zf4, 0, 0, 0);
            f4 sb = __builtin_amdgcn_mfma_f32_16x16x32_bf16(kk1, qf[f], zf4, 0, 0, 0);
            f4 ea, eb;
            #pragma unroll
            for (int r = 0; r < 4; ++r) {
                ea[r] = __builtin_amdgcn_exp2f(sa[r]);   // scores pre-scaled by log2e
                eb[r] = __builtin_amdgcn_exp2f(sb[r]);
            }
            u32x4 pd;
            pd[0] = pktr(ea[0], ea[1]); pd[1] = pktr(ea[2], ea[3]);
            pd[2] = pktr(eb[0], eb[1]); pd[3] = pktr(eb[2], eb[3]);
            s8v pf = __builtin_bit_cast(s8v, pd);

            accl[f]   = __builtin_amdgcn_mfma_f32_16x16x32_bf16(ones, pf, accl[f],   0, 0, 0);
            acc[f][0] = __builtin_amdgcn_mfma_f32_16x16x32_bf16(v0,   pf, acc[f][0], 0, 0, 0);
            acc[f][1] = __builtin_amdgcn_mfma_f32_16x16x32_bf16(v1,   pf, acc[f][1], 0, 0, 0);
            acc[f][2] = __builtin_amdgcn_mfma_f32_16x16x32_bf16(v2,   pf, acc[f][2], 0, 0, 0);
            acc[f][3] = __builtin_amdgcn_mfma_f32_16x16x32_bf16(v3,   pf, acc[f][3], 0, 0, 0);
        }
    }

    // ---- write this wave's partial into its slot ----
    #pragma unroll
    for (int f = 0; f < 4; ++f) {
        const int row = f * 16 + ln;
        if (quad == 0) lbuf[w][row] = accl[f][0];
        #pragma unroll
        for (int ct = 0; ct < 4; ++ct) {
            u32x2 pw;
            pw[0] = pk2(acc[f][ct][0], acc[f][ct][1]);
            pw[1] = pk2(acc[f][ct][2], acc[f][ct][3]);
            *(u32x2*)&slots[w][row * 68 + ct * 16 + quad * 4] = pw;
        }
    }
    __syncthreads();

    // ---- single-phase 8-way combine by all 512 threads ----
    {
        const int q = tid >> 3;            // query row 0..63
        const int e = (tid & 7) * 8;       // channel group of 8
        float ls = 0.f;
        #pragma unroll
        for (int s = 0; s < 8; ++s) ls += lbuf[s][q];
        const float rl = __builtin_amdgcn_rcpf(ls);
        float zv[8];
        #pragma unroll
        for (int i = 0; i < 8; ++i) zv[i] = 0.f;
        #pragma unroll
        for (int s = 0; s < 8; ++s) {
            u32x2 a = *(const u32x2*)&slots[s][q * 68 + e];
            u32x2 c = *(const u32x2*)&slots[s][q * 68 + e + 4];
            zv[0] += bflo(a[0]); zv[1] += bfhi(a[0]);
            zv[2] += bflo(a[1]); zv[3] += bfhi(a[1]);
            zv[4] += bflo(c[0]); zv[5] += bfhi(c[0]);
            zv[6] += bflo(c[1]); zv[7] += bfhi(c[1]);
        }
        __syncthreads();                   // all slot reads done before zbuf alias write
        u32x2 o0, o1;
        o0[0] = pk2(zv[0] * rl, zv[1] * rl);
        o0[1] = pk2(zv[2] * rl, zv[3] * rl);
        o1[0] = pk2(zv[4] * rl, zv[5] * rl);
        o1[1] = pk2(zv[6] * rl, zv[7] * rl);
        *(u32x2*)&zbuf[q * 72 + e]     = o0;
        *(u32x2*)&zbuf[q * 72 + e + 4] = o1;
    }
    __syncthreads();

    // ---- out-projection: wave w -> o-tile (w&3), query half (w>>2) ----
    {
        const int ot = w & 3, half = w >> 2;
        s8v wzf[2];
        #pragma unroll
        for (int hh = 0; hh < 2; ++hh) {
            const float* wp = wz + (ot * 16 + ln) * 64 + hh * 32 + quad * 8;
            f4 wa = *(const f4*)wp;
            f4 wb = *(const f4*)(wp + 4);
            u32x4 tt;
            tt[0] = pk2(wa[0], wa[1]); tt[1] = pk2(wa[2], wa[3]);
            tt[2] = pk2(wb[0], wb[1]); tt[3] = pk2(wb[2], wb[3]);
            wzf[hh] = __builtin_bit_cast(s8v, tt);
        }
        f4 bzv = *(const f4*)(bz + ot * 16 + quad * 4);
        #pragma unroll
        for (int fi = 0; fi < 2; ++fi) {
            const int row = (half * 2 + fi) * 16 + ln;
            s8v z0 = *(const s8v*)&zbuf[row * 72 + quad * 8];
            s8v z1 = *(const s8v*)&zbuf[row * 72 + 32 + quad * 8];
            f4 oa = __builtin_amdgcn_mfma_f32_16x16x32_bf16(wzf[0], z0, zf4, 0, 0, 0);
            oa     = __builtin_amdgcn_mfma_f32_16x16x32_bf16(wzf[1], z1, oa,  0, 0, 0);
            #pragma unroll
            for (int r = 0; r < 4; ++r) {
                size_t idx = ((size_t)(b * CIN + ot * 16 + quad * 4 + r)) * NTOK
                           + qb0 + row;
                out[idx] = oa[r] + bzv[r] + h[idx];
            }
        }
    }
}

extern "C" void kernel_launch(void* const* d_in, const int* in_sizes, int n_in,
                              void* d_out, int out_size, void* d_ws, size_t ws_size,
                              hipStream_t stream) {
    (void)in_sizes; (void)n_in; (void)out_size; (void)ws_size;
    const float* h  = (const float*)d_in[0];
    const float* wq = (const float*)d_in[1];
    const float* bq = (const float*)d_in[2];
    const float* wk = (const float*)d_in[3];
    const float* bk = (const float*)d_in[4];
    const float* wv = (const float*)d_in[5];
    const float* bv = (const float*)d_in[6];
    const float* wz = (const float*)d_in[7];
    const float* bz = (const float*)d_in[8];
    float* out = (float*)d_out;

    short* qbf = (short*)d_ws;                                // 8*4096*32
    short* kbf = qbf + (size_t)BATCH * NTOK * DH;             // 8*4096*32
    short* vpw = kbf + (size_t)BATCH * NTOK * DH;             // 8*4096*64

    proj_kernel<<<dim3(8, 64), dim3(256), 0, stream>>>(
        h, wq, bq, wk, bk, wv, bv, qbf, kbf, vpw);
    attn_kernel<<<dim3(8, 64), dim3(512), 0, stream>>>(
        h, wz, bz, qbf, kbf, vpw, out);
}

// Round 9
// 120.101 us; speedup vs baseline: 1.7532x; 1.7532x over previous
//
#include <hip/hip_runtime.h>
#include <stdint.h>

#define BATCH 8
#define CIN   64
#define DH    32
#define NTOK  4096
#define LOG2E 1.4426950408889634f

typedef float    f4   __attribute__((ext_vector_type(4)));
typedef short    s8v  __attribute__((ext_vector_type(8)));
typedef uint32_t u32;
typedef uint32_t u32x2 __attribute__((ext_vector_type(2)));
typedef uint32_t u32x4 __attribute__((ext_vector_type(4)));

static __device__ __forceinline__ short f2bf(float f) {       // RNE
    union { float f; u32 u; } c; c.f = f;
    u32 u = c.u;
    u32 r = (u + 0x7fffu + ((u >> 16) & 1u)) >> 16;
    return (short)(r & 0xffffu);
}
static __device__ __forceinline__ u32 pk2(float a, float b) { // RNE pack
    return (u32)(uint16_t)f2bf(a) | ((u32)(uint16_t)f2bf(b) << 16);
}
static __device__ __forceinline__ u32 pktr(float a, float b) { // truncate pack (fast)
    union { float f; u32 u; } ca, cb; ca.f = a; cb.f = b;
#if __has_builtin(__builtin_amdgcn_perm)
    return __builtin_amdgcn_perm(cb.u, ca.u, 0x07060302u);
#else
    return (cb.u & 0xffff0000u) | (ca.u >> 16);
#endif
}
static __device__ __forceinline__ float bfhi(u32 u) {
    union { u32 u; float f; } c; c.u = u & 0xffff0000u; return c.f;
}
static __device__ __forceinline__ float bflo(u32 u) {
    union { u32 u; float f; } c; c.u = u << 16; return c.f;
}

// ---------------------------------------------------------------------------
// Kernel 1: MFMA QKV projection (unchanged since round 4 — passed, ~4 us).
// ---------------------------------------------------------------------------
__global__ __launch_bounds__(256) void proj_kernel(
    const float* __restrict__ h,
    const float* __restrict__ wq, const float* __restrict__ bq,
    const float* __restrict__ wk, const float* __restrict__ bk,
    const float* __restrict__ wv, const float* __restrict__ bv,
    short* __restrict__ qbf, short* __restrict__ kbf, short* __restrict__ vp)
{
    __shared__ short xT [64 * 72];   // [n_local][c] bf16
    __shared__ short wqs[32 * 72];   // [o][c] bf16 (pre-scaled by log2e)
    __shared__ short wks[32 * 72];
    __shared__ short wvs[64 * 72];
    __shared__ short vls2[64 * 68];  // [row=cid2*32+qq*8+j][ch], pad 68
    __shared__ float bqs[32], bks[32], bvs[64];

    const int t   = threadIdx.x;
    const int b   = blockIdx.x;
    const int nt0 = blockIdx.y * 64;

    { // stage x tile: coalesced global reads, bf16 transpose into LDS
        const int c  = t >> 2;
        const int ng = (t & 3) * 16;
        const float* src = h + ((size_t)(b * CIN + c)) * NTOK + nt0 + ng;
        f4 x0 = *(const f4*)(src + 0);
        f4 x1 = *(const f4*)(src + 4);
        f4 x2 = *(const f4*)(src + 8);
        f4 x3 = *(const f4*)(src + 12);
        #pragma unroll
        for (int i = 0; i < 4; ++i) {
            xT[(ng + 0  + i) * 72 + c] = f2bf(x0[i]);
            xT[(ng + 4  + i) * 72 + c] = f2bf(x1[i]);
            xT[(ng + 8  + i) * 72 + c] = f2bf(x2[i]);
            xT[(ng + 12 + i) * 72 + c] = f2bf(x3[i]);
        }
    }
    for (int idx = t; idx < 2048; idx += 256) {
        int o = idx >> 6, c = idx & 63;
        wqs[o * 72 + c] = f2bf(wq[idx] * LOG2E);
        wks[o * 72 + c] = f2bf(wk[idx]);
    }
    for (int idx = t; idx < 4096; idx += 256)
        wvs[(idx >> 6) * 72 + (idx & 63)] = f2bf(wv[idx]);
    if (t < 32) { bqs[t] = bq[t] * LOG2E; bks[t] = bk[t]; }
    if (t < 64) bvs[t] = bv[t];
    __syncthreads();

    const int w    = t >> 6;
    const int ln   = t & 15;
    const int quad = (t >> 4) & 3;
    const int nl   = w * 16 + ln;
    const int n    = nt0 + nl;
    const f4 zf4 = {0.f, 0.f, 0.f, 0.f};

    const s8v xb0 = *(const s8v*)&xT[nl * 72 + quad * 8];
    const s8v xb1 = *(const s8v*)&xT[nl * 72 + 32 + quad * 8];

    #pragma unroll
    for (int ot = 0; ot < 2; ++ot) {
        s8v a0 = *(const s8v*)&wqs[(ot * 16 + ln) * 72 + quad * 8];
        s8v a1 = *(const s8v*)&wqs[(ot * 16 + ln) * 72 + 32 + quad * 8];
        f4 d = __builtin_amdgcn_mfma_f32_16x16x32_bf16(a0, xb0, zf4, 0, 0, 0);
        d     = __builtin_amdgcn_mfma_f32_16x16x32_bf16(a1, xb1, d,  0, 0, 0);
        f4 bb = *(const f4*)&bqs[ot * 16 + quad * 4];
        u32x2 pw; pw[0] = pk2(d[0] + bb[0], d[1] + bb[1]);
                  pw[1] = pk2(d[2] + bb[2], d[3] + bb[3]);
        *(u32x2*)(qbf + ((size_t)(b * NTOK + n)) * DH + ot * 16 + quad * 4) = pw;

        s8v c0 = *(const s8v*)&wks[(ot * 16 + ln) * 72 + quad * 8];
        s8v c1 = *(const s8v*)&wks[(ot * 16 + ln) * 72 + 32 + quad * 8];
        f4 e = __builtin_amdgcn_mfma_f32_16x16x32_bf16(c0, xb0, zf4, 0, 0, 0);
        e     = __builtin_amdgcn_mfma_f32_16x16x32_bf16(c1, xb1, e,  0, 0, 0);
        f4 kb = *(const f4*)&bks[ot * 16 + quad * 4];
        u32x2 kw; kw[0] = pk2(e[0] + kb[0], e[1] + kb[1]);
                  kw[1] = pk2(e[2] + kb[2], e[3] + kb[3]);
        *(u32x2*)(kbf + ((size_t)(b * NTOK + n)) * DH + ot * 16 + quad * 4) = kw;
    }

    {
        const int p    = nl & 31;
        const int row  = (nl >> 5) * 32 + ((p >> 2) & 3) * 8
                       + (p >> 4) * 4 + (p & 3);
        short* vrow = &vls2[row * 68];
        #pragma unroll
        for (int ot = 0; ot < 4; ++ot) {
            s8v a0 = *(const s8v*)&wvs[(ot * 16 + ln) * 72 + quad * 8];
            s8v a1 = *(const s8v*)&wvs[(ot * 16 + ln) * 72 + 32 + quad * 8];
            f4 d = __builtin_amdgcn_mfma_f32_16x16x32_bf16(a0, xb0, zf4, 0, 0, 0);
            d     = __builtin_amdgcn_mfma_f32_16x16x32_bf16(a1, xb1, d,  0, 0, 0);
            const int ch = ot * 16 + quad * 4;
            u32x2 pw;
            pw[0] = pk2(d[0] + bvs[ch],     d[1] + bvs[ch + 1]);
            pw[1] = pk2(d[2] + bvs[ch + 2], d[3] + bvs[ch + 3]);
            *(u32x2*)&vrow[ch] = pw;
        }
    }
    __syncthreads();

    {
        const int g = t >> 5;
        const int r = t & 31;
        short tmp[16];
        #pragma unroll
        for (int j = 0; j < 8; ++j)
            #pragma unroll
            for (int cc = 0; cc < 2; ++cc)
                tmp[cc * 8 + j] = vls2[(g * 8 + j) * 68 + r * 2 + cc];
        u32x4* dst = (u32x4*)(vp + ((size_t)(b * 128 + blockIdx.y * 2) * 4) * 64 * 8);
        #pragma unroll
        for (int i = 0; i < 2; ++i)
            dst[t * 2 + i] = ((const u32x4*)tmp)[i];
    }
}

// ---------------------------------------------------------------------------
// Kernel 2: max-free flash attention + Wz projection + residual.
// TLP with SMALL waves (round-8 spilled at 64q/wave under a 128-reg cap):
// 512 thr = 8 waves = 2 query-halves (qg=w&1) x 4 key-quarters (kh=w>>1),
// 32 queries (2 frags) per wave -> ~100 unified regs, fits 4 waves/SIMD
// WITHOUT launch-bounds coercion (bounds (512,2): cap 256, no spill).
// grid (8,64) -> 2 blocks/CU = 16 waves/CU = 4 waves/SIMD. The qg-pair of
// each kh-stream reads the same 6KB tile on the same CU -> L1 absorbs the
// duplicate. K-loop: plain compiler-scheduled (R6/R7: do not hand-pipeline).
// ---------------------------------------------------------------------------
__global__ __launch_bounds__(512, 2) void attn_kernel(
    const float* __restrict__ h,  const float* __restrict__ wz,
    const float* __restrict__ bz,
    const short* __restrict__ qbf, const short* __restrict__ kbf,
    const short* __restrict__ vp,  float* __restrict__ out)
{
    __shared__ short slots[8][32 * 68];   // per-wave partials, 34.8 KB
    __shared__ float lbuf[8][32];         // per-wave partial l
    short* zbuf = (short*)slots;          // alias after combine, stride 72

    const int b    = blockIdx.x;          // XCD-affine: linear%8 == b
    const int qb0  = blockIdx.y * 64;
    const int tid  = threadIdx.x;
    const int w    = tid >> 6;
    const int lane = tid & 63;
    const int ln   = lane & 15;
    const int quad = lane >> 4;
    const int qg   = w & 1;               // query half (32 q)
    const int kh   = w >> 1;              // key quarter (1024 keys)
    const f4 zf4 = {0.f, 0.f, 0.f, 0.f};

    // Q fragments (B-operand): B[d=quad*8+j][n=ln]
    s8v qf[2];
    #pragma unroll
    for (int f = 0; f < 2; ++f)
        qf[f] = *(const s8v*)(qbf +
            ((size_t)(b * NTOK + qb0 + qg * 32 + f * 16 + ln)) * DH + quad * 8);

    f4 acc[2][4];
    f4 accl[2];
    #pragma unroll
    for (int f = 0; f < 2; ++f) {
        accl[f] = zf4;
        #pragma unroll
        for (int ct = 0; ct < 4; ++ct) acc[f][ct] = zf4;
    }
    s8v ones;
    #pragma unroll
    for (int j = 0; j < 8; ++j) ones[j] = (short)0x3F80;   // bf16 1.0

    const short* kb2 = kbf + ((size_t)b * NTOK + kh * 1024) * DH;
    const s8v*   vb2 = (const s8v*)(vp + (size_t)b * NTOK * CIN)
                     + (size_t)(kh * 32) * 4 * 64;

    for (int kt = 0; kt < 1024; kt += 32) {
        const short* kp = kb2 + kt * DH;
        s8v kk0 = *(const s8v*)(kp + ln * DH + quad * 8);
        s8v kk1 = *(const s8v*)(kp + (16 + ln) * DH + quad * 8);
        const s8v* vg = vb2 + (size_t)((kt >> 5) * 4 + quad) * 64 + ln;
        s8v v0 = vg[0], v1 = vg[16], v2 = vg[32], v3 = vg[48];

        #pragma unroll
        for (int f = 0; f < 2; ++f) {
            f4 sa = __builtin_amdgcn_mfma_f32_16x16x32_bf16(kk0, qf[f], zf4, 0, 0, 0);
            f4 sb = __builtin_amdgcn_mfma_f32_16x16x32_bf16(kk1, qf[f], zf4, 0, 0, 0);
            f4 ea, eb;
            #pragma unroll
            for (int r = 0; r < 4; ++r) {
                ea[r] = __builtin_amdgcn_exp2f(sa[r]);   // scores pre-scaled by log2e
                eb[r] = __builtin_amdgcn_exp2f(sb[r]);
            }
            u32x4 pd;
            pd[0] = pktr(ea[0], ea[1]); pd[1] = pktr(ea[2], ea[3]);
            pd[2] = pktr(eb[0], eb[1]); pd[3] = pktr(eb[2], eb[3]);
            s8v pf = __builtin_bit_cast(s8v, pd);

            accl[f]   = __builtin_amdgcn_mfma_f32_16x16x32_bf16(ones, pf, accl[f],   0, 0, 0);
            acc[f][0] = __builtin_amdgcn_mfma_f32_16x16x32_bf16(v0,   pf, acc[f][0], 0, 0, 0);
            acc[f][1] = __builtin_amdgcn_mfma_f32_16x16x32_bf16(v1,   pf, acc[f][1], 0, 0, 0);
            acc[f][2] = __builtin_amdgcn_mfma_f32_16x16x32_bf16(v2,   pf, acc[f][2], 0, 0, 0);
            acc[f][3] = __builtin_amdgcn_mfma_f32_16x16x32_bf16(v3,   pf, acc[f][3], 0, 0, 0);
        }
    }

    // ---- write this wave's partial into its slot ----
    #pragma unroll
    for (int f = 0; f < 2; ++f) {
        const int row = f * 16 + ln;      // 0..31 within the wave's 32 queries
        if (quad == 0) lbuf[w][row] = accl[f][0];
        #pragma unroll
        for (int ct = 0; ct < 4; ++ct) {
            u32x2 pw;
            pw[0] = pk2(acc[f][ct][0], acc[f][ct][1]);
            pw[1] = pk2(acc[f][ct][2], acc[f][ct][3]);
            *(u32x2*)&slots[w][row * 68 + ct * 16 + quad * 4] = pw;
        }
    }
    __syncthreads();

    // ---- single-phase 4-way combine by all 512 threads ----
    {
        const int row = tid >> 3;          // block-local query row 0..63
        const int g   = row >> 5;          // which query half
        const int rq  = row & 31;          // row within half
        const int e   = (tid & 7) * 8;     // channel group of 8
        float ls = 0.f;
        #pragma unroll
        for (int s = 0; s < 4; ++s) ls += lbuf[s * 2 + g][rq];
        const float rl = __builtin_amdgcn_rcpf(ls);
        float zv[8];
        #pragma unroll
        for (int i = 0; i < 8; ++i) zv[i] = 0.f;
        #pragma unroll
        for (int s = 0; s < 4; ++s) {
            u32x2 a = *(const u32x2*)&slots[s * 2 + g][rq * 68 + e];
            u32x2 c = *(const u32x2*)&slots[s * 2 + g][rq * 68 + e + 4];
            zv[0] += bflo(a[0]); zv[1] += bfhi(a[0]);
            zv[2] += bflo(a[1]); zv[3] += bfhi(a[1]);
            zv[4] += bflo(c[0]); zv[5] += bfhi(c[0]);
            zv[6] += bflo(c[1]); zv[7] += bfhi(c[1]);
        }
        __syncthreads();                   // slot reads done before alias write
        u32x2 o0, o1;
        o0[0] = pk2(zv[0] * rl, zv[1] * rl);
        o0[1] = pk2(zv[2] * rl, zv[3] * rl);
        o1[0] = pk2(zv[4] * rl, zv[5] * rl);
        o1[1] = pk2(zv[6] * rl, zv[7] * rl);
        *(u32x2*)&zbuf[row * 72 + e]     = o0;
        *(u32x2*)&zbuf[row * 72 + e + 4] = o1;
    }
    __syncthreads();

    // ---- out-projection: wave w -> o-tile (w&3), query half (w>>2) ----
    {
        const int ot = w & 3, half = w >> 2;
        s8v wzf[2];
        #pragma unroll
        for (int hh = 0; hh < 2; ++hh) {
            const float* wp = wz + (ot * 16 + ln) * 64 + hh * 32 + quad * 8;
            f4 wa = *(const f4*)wp;
            f4 wb = *(const f4*)(wp + 4);
            u32x4 tt;
            tt[0] = pk2(wa[0], wa[1]); tt[1] = pk2(wa[2], wa[3]);
            tt[2] = pk2(wb[0], wb[1]); tt[3] = pk2(wb[2], wb[3]);
            wzf[hh] = __builtin_bit_cast(s8v, tt);
        }
        f4 bzv = *(const f4*)(bz + ot * 16 + quad * 4);
        #pragma unroll
        for (int fi = 0; fi < 2; ++fi) {
            const int row = half * 32 + fi * 16 + ln;
            s8v z0 = *(const s8v*)&zbuf[row * 72 + quad * 8];
            s8v z1 = *(const s8v*)&zbuf[row * 72 + 32 + quad * 8];
            f4 oa = __builtin_amdgcn_mfma_f32_16x16x32_bf16(wzf[0], z0, zf4, 0, 0, 0);
            oa     = __builtin_amdgcn_mfma_f32_16x16x32_bf16(wzf[1], z1, oa,  0, 0, 0);
            #pragma unroll
            for (int r = 0; r < 4; ++r) {
                size_t idx = ((size_t)(b * CIN + ot * 16 + quad * 4 + r)) * NTOK
                           + qb0 + row;
                out[idx] = oa[r] + bzv[r] + h[idx];
            }
        }
    }
}

extern "C" void kernel_launch(void* const* d_in, const int* in_sizes, int n_in,
                              void* d_out, int out_size, void* d_ws, size_t ws_size,
                              hipStream_t stream) {
    (void)in_sizes; (void)n_in; (void)out_size; (void)ws_size;
    const float* h  = (const float*)d_in[0];
    const float* wq = (const float*)d_in[1];
    const float* bq = (const float*)d_in[2];
    const float* wk = (const float*)d_in[3];
    const float* bk = (const float*)d_in[4];
    const float* wv = (const float*)d_in[5];
    const float* bv = (const float*)d_in[6];
    const float* wz = (const float*)d_in[7];
    const float* bz = (const float*)d_in[8];
    float* out = (float*)d_out;

    short* qbf = (short*)d_ws;                                // 8*4096*32
    short* kbf = qbf + (size_t)BATCH * NTOK * DH;             // 8*4096*32
    short* vpw = kbf + (size_t)BATCH * NTOK * DH;             // 8*4096*64

    proj_kernel<<<dim3(8, 64), dim3(256), 0, stream>>>(
        h, wq, bq, wk, bk, wv, bv, qbf, kbf, vpw);
    attn_kernel<<<dim3(8, 64), dim3(512), 0, stream>>>(
        h, wz, bz, qbf, kbf, vpw, out);
}